// Round 12
// baseline (27034.113 us; speedup 1.0000x reference)
//
#include <hip/hip_runtime.h>
#include <hip/hip_fp16.h>
#include <math.h>

// 2-layer LSTM decoder, H=100, T=8192 encode + F=1024 future steps, fp32 state.
// Three persistent blocks (3 CUs), 256 threads (4 waves) each, 2 rows/thread:
//   block 0 (A) : layer-1 recurrence. gates1 = w_ih1*x + w_hh1*h1 + b. h1 -> ring1.
//   block 1 (A2): feed-forward pre2 = w_ih2*h1 + biases. ring1 -> ring2.
//   block 2 (B) : layer-2 recurrence gates2 = pre2 + w_hh2*h2; y = h2.w_lin + b.
//
// V12: FP16 STREAMING, SCHEDULING-CLEAN. V11 (fp16, 26.4ms vs V5 fp32 16.0ms)
// falsified the BW model: FETCH flat (weights DO come from L2) and stalls rose
// +2100cy/step. V5 is latency/scheduling-bound (41B/cy = 73% of L2 port).
// V11's dot broke scheduling three ways: (1) weight loads shared the `ws`
// restrict root with in-loop atomic ring stores -> AA may-alias -> no load
// batching; (2) (const __half2*)&local defeats SROA -> scratch risk; (3) +208
// cvts raised pressure. V12 removes all three, keeps the half-bytes win:
//   * fp16 weight area passed as a SEPARATE __restrict__ param (distinct root).
//   * uint4 loads consumed directly by v_fma_mix_f32 inline asm (op_sel picks
//     the fp16 half; fp32 accumulate; no cvt, no address-casts, non-volatile
//     asm -> freely schedulable). Bit-identical math to V11 (absmax 4.9e-4).
//
// Sync design (V3..V6-proven, byte-identical):
//  * Cross-CU data via relaxed agent atomics; ordering via s_waitcnt vmcnt only
//    (producer: vmcnt(0) before flag store; consumer: vmcnt(0) after flag obs).
//    NO agent fences (whole-L2 wbl2/inv = V2 regression).
//  * Per-wave flags aw[4]/p2w[4]; consumers take min4. Producers publish at
//    top-of-next-iteration (store acks aged ~1 iter -> vmcnt cheap).
//  * A/B: raw s_barrier + lgkmcnt(0) (LDS-only drain; ring stores in flight).
//    A2: counted vmcnt(2) certify (~30 vm-ops/iter -> slot t-3 store >=2 iters
//    back), 1-deep prefetch pipeline in encode, straight mode in future.
//  * Flags monotone <= 9217 -> 0xAA workspace poison sanitizes to 0.
//  * fp16 weights re-converted every launch in ws -> poison-safe.

#define HH 100
#define NT 256
#define ROWS 400
#define RPAD 104           // padded row length in halves (208B, 16B-aligned)
#define SPIN_CAP 2000000u

#define OFF_AW     0       // unsigned aw[4]  : A per-wave publish counters
#define OFF_P2W    128     // unsigned p2w[4] : A2 per-wave publish counters
#define OFF_BPROG  256     // unsigned        : B consumption counter
#define OFF_YPROG  384     // unsigned        : y produced counter
#define OFF_YSLOT  512     // float[F+1]
#define OFF_WC     4096    // 3 x 400x104 halves = 249,600 B converted weights
#define OFF_RING   262144

#define VMCNT0() asm volatile("s_waitcnt vmcnt(0)" ::: "memory")
#define VMCNT2() asm volatile("s_waitcnt vmcnt(2)" ::: "memory")
#define LGKM0()  asm volatile("s_waitcnt lgkmcnt(0)" ::: "memory")
#define CLOB()   asm volatile("" ::: "memory")

__device__ __forceinline__ float rl(float v, int k) {
    return __int_as_float(__builtin_amdgcn_readlane(__float_as_int(v), k));
}
__device__ __forceinline__ unsigned san(unsigned v) { return v > 0x00FFFFFFu ? 0u : v; }
__device__ __forceinline__ unsigned ldu(const unsigned* p) {
    return san(__hip_atomic_load((unsigned*)p, __ATOMIC_RELAXED, __HIP_MEMORY_SCOPE_AGENT));
}
__device__ __forceinline__ void stu(unsigned* p, unsigned v) {
    __hip_atomic_store(p, v, __ATOMIC_RELAXED, __HIP_MEMORY_SCOPE_AGENT);
}
__device__ __forceinline__ float ld_f(const float* p) {
    return __hip_atomic_load((float*)p, __ATOMIC_RELAXED, __HIP_MEMORY_SCOPE_AGENT);
}
__device__ __forceinline__ void st_wt(float* p, float v) {
    __hip_atomic_store(p, v, __ATOMIC_RELAXED, __HIP_MEMORY_SCOPE_AGENT);
}
__device__ __forceinline__ void wait_ge(unsigned* p, unsigned need, unsigned& cache) {
    if (cache >= need) return;
    unsigned s = 0;
    do { cache = ldu(p); } while (cache < need && ++s < SPIN_CAP);
    VMCNT0();
}
__device__ __forceinline__ void wait_min4(unsigned* q, unsigned need, unsigned& cache) {
    if (cache >= need) return;
    unsigned s = 0;
    for (;;) {
        unsigned m0 = ldu(q), m1 = ldu(q + 1), m2 = ldu(q + 2), m3 = ldu(q + 3);
        unsigned a = m0 < m1 ? m0 : m1, b = m2 < m3 ? m2 : m3;
        cache = a < b ? a : b;
        if (cache >= need || ++s > SPIN_CAP) break;
    }
    VMCNT0();
}
// Raw workgroup barrier: LDS drain only (ring stores stay in flight).
__device__ __forceinline__ void bar() {
    LGKM0();
    __builtin_amdgcn_s_barrier();
    CLOB();
}
__device__ __forceinline__ float fast_sigm(float x) {
    return __builtin_amdgcn_rcpf(1.0f + __expf(-x));
}
__device__ __forceinline__ float fast_tanh(float x) {
    return fmaf(-2.0f, __builtin_amdgcn_rcpf(1.0f + __expf(2.0f * x)), 1.0f);
}

// acc += (fp16 half of w) * h, fp32 accumulate. op_sel[0] picks lo/hi half of
// the packed u32; op_sel_hi:[1,0,0] marks src0 as fp16, src1/src2 fp32.
// Non-volatile: scheduler may interleave freely with loads/readlanes.
#define MIXLO(acc, wv, hv) asm("v_fma_mix_f32 %0, %1, %2, %0 op_sel:[0,0,0] op_sel_hi:[1,0,0]" \
                               : "+v"(acc) : "v"(wv), "v"(hv))
#define MIXHI(acc, wv, hv) asm("v_fma_mix_f32 %0, %1, %2, %0 op_sel:[1,0,0] op_sel_hi:[1,0,0]" \
                               : "+v"(acc) : "v"(wv), "v"(hv))

// ---- fp16 weight dot: 13 chunks x 8 halves x 2 rows ----
// chunk c covers h[8c..8c+7]; c<8 broadcasts from hv0 (lanes 8c..), c>=8 from
// hv1 (lanes 8c-64..). Chunk 12 covers k=96..103: pad weights (k>=100) are 0
// and the matching hv1 broadcast lanes (36..39) hold 0. fp32 accumulation.
#define REP13(M) M(0) M(1) M(2) M(3) M(4) M(5) M(6) M(7) M(8) M(9) M(10) M(11) M(12)
#define DOTC(c) { \
    const float hsv = ((c) < 8) ? hv0 : hv1; \
    const int kb = ((c) < 8) ? (8 * (c)) : (8 * (c) - 64); \
    uint4 Wa = w0p[c]; \
    uint4 Wb = w1p[c]; \
    float h0 = rl(hsv, kb),     h1 = rl(hsv, kb + 1), h2 = rl(hsv, kb + 2), h3 = rl(hsv, kb + 3); \
    float h4 = rl(hsv, kb + 4), h5 = rl(hsv, kb + 5), h6 = rl(hsv, kb + 6), h7 = rl(hsv, kb + 7); \
    MIXLO(a0, Wa.x, h0); MIXHI(a1, Wa.x, h1); \
    MIXLO(a0, Wa.y, h2); MIXHI(a1, Wa.y, h3); \
    MIXLO(a0, Wa.z, h4); MIXHI(a1, Wa.z, h5); \
    MIXLO(a0, Wa.w, h6); MIXHI(a1, Wa.w, h7); \
    MIXLO(b0, Wb.x, h0); MIXHI(b1, Wb.x, h1); \
    MIXLO(b0, Wb.y, h2); MIXHI(b1, Wb.y, h3); \
    MIXLO(b0, Wb.z, h4); MIXHI(b1, Wb.z, h5); \
    MIXLO(b0, Wb.w, h6); MIXHI(b1, Wb.w, h7); \
}

extern "C" __global__ void __launch_bounds__(NT)
__attribute__((amdgpu_waves_per_eu(1, 1)))
decoder_kernel(const float* __restrict__ input,
               const float* __restrict__ enc_h,
               const float* __restrict__ enc_c,
               const float* __restrict__ w_ih1,
               const float* __restrict__ w_hh1,
               const float* __restrict__ b_ih1,
               const float* __restrict__ b_hh1,
               const float* __restrict__ w_ih2,
               const float* __restrict__ w_hh2,
               const float* __restrict__ b_ih2,
               const float* __restrict__ b_hh2,
               const float* __restrict__ w_lin,
               const float* __restrict__ b_lin,
               float* __restrict__ out,
               char* __restrict__ ws,
               __half* __restrict__ wfp16,     // = ws + OFF_WC, DISTINCT restrict root
               int T, int F, int S)
{
    const int tid = threadIdx.x;
    const int l = tid & 63;
    const int w = tid >> 6;
    unsigned* aw     = (unsigned*)(ws + OFF_AW);
    unsigned* p2w    = (unsigned*)(ws + OFF_P2W);
    unsigned* b_prog = (unsigned*)(ws + OFF_BPROG);
    unsigned* y_prog = (unsigned*)(ws + OFF_YPROG);
    float* y_slot = (float*)(ws + OFF_YSLOT);
    float* ring1  = (float*)(ws + OFF_RING);
    float* ring2  = ring1 + (size_t)S * HH;
    const int smask = S - 1;
    const int TOT = T + F;
    const int bid = blockIdx.x;

    // ---- one-time: convert THIS block's matrix to fp16 (padded rows).
    // All wfp16 accesses (write here, read in loop) go through this root only;
    // ws-root accesses (rings/flags) never touch this region.
    __half* wc = wfp16 + (size_t)bid * (ROWS * RPAD);
    {
        const float* wsrc = (bid == 0) ? w_hh1 : (bid == 1) ? w_ih2 : w_hh2;
        for (int i = tid; i < ROWS * RPAD; i += NT) {
            int r = i / RPAD, c = i - r * RPAD;
            wc[i] = __float2half(c < HH ? wsrc[r * HH + c] : 0.f);
        }
    }

    // Gate lane mapping (A and B): wave w owns cells 25w..25w+24.
    // lanes 0-24: rows cell (i), cell+100 (f); lanes 32-56: cell+200 (g), cell+300 (o).
    const bool gi_lane = (l < 25);
    const bool go_lane = (l >= 32 && l < 57);
    const int cell = 25 * w + (gi_lane ? l : (go_lane ? (l - 32) : 0));
    const int gj0 = gi_lane ? cell : (go_lane ? cell + 200 : 0);
    const int gj1 = gi_lane ? cell + 100 : (go_lane ? cell + 300 : 0);

    if (bid == 0) {
        // ================= A: layer-1 recurrence =================
        __shared__ __align__(16) float h1s[2][128];
        const uint4* w0p = (const uint4*)(wc + (size_t)gj0 * RPAD);
        const uint4* w1p = (const uint4*)(wc + (size_t)gj1 * RPAD);
        const float wx0 = w_ih1[gj0];
        const float wx1 = w_ih1[gj1];
        const float bi0 = b_ih1[gj0] + b_hh1[gj0];
        const float bi1 = b_ih1[gj1] + b_hh1[gj1];
        float cst = gi_lane ? enc_c[cell] : 0.f;
        if (tid < 128) {
            h1s[0][tid] = (tid < HH) ? enc_h[tid] : 0.f;
            h1s[1][tid] = 0.f;
        }
        __syncthreads();   // publishes fp16 conversion (vmcnt drain) + h1s init

        unsigned cp2 = 0, cy = 0;
        for (int t = 0; t < TOT; ++t) {
            // publish slot t-1: ring1 stores aged ~1 iteration -> vmcnt(0) cheap.
            VMCNT0();
            if (l == 0 && t > 0) stu(&aw[w], (unsigned)t);     // slots <= t-1 valid
            float x = 0.f;
            if (t < T) x = input[t];
            // ring1 overwrite guard: A2 consumed slot t-S when min(p2w) >= t-S+1
            if (t >= S) wait_min4(p2w, (unsigned)(t - S + 1), cp2);
            float hv0 = h1s[t & 1][l];
            float hv1 = h1s[t & 1][64 + l];    // slots 100-127 stay 0
            float a0 = 0.f, a1 = 0.f, b0 = 0.f, b1 = 0.f;
            REP13(DOTC)
            float accA = bi0 + a0 + a1;
            float accB = bi1 + b0 + b1;
            if (t >= T) {                       // future: dot done, now wait for y
                wait_ge(y_prog, (unsigned)(t - T + 1), cy);
                x = ld_f(&y_slot[t - T]);
            }
            accA = fmaf(x, wx0, accA);
            accB = fmaf(x, wx1, accB);
            float vA = go_lane ? fast_tanh(accA) : fast_sigm(accA);  // i or g
            float vB = fast_sigm(accB);                              // f or o
            float gg = __shfl_xor(vA, 32);
            float go = __shfl_xor(vB, 32);
            if (gi_lane) {
                cst = fmaf(vB, cst, vA * gg);
                float h = go * fast_tanh(cst);
                h1s[(t + 1) & 1][cell] = h;
                st_wt(&ring1[(size_t)(t & smask) * HH + cell], h);
            }
            bar();    // LDS-only drain; ring1 stores stay in flight across it
        }
        VMCNT0();
        if (l == 0) stu(&aw[w], (unsigned)TOT);
    } else if (bid == 1) {
        // ===== A2: pre2 = w_ih2*h1 + biases. 4 independent waves, no barriers. =====
        const bool has2 = tid < (ROWS - NT);   // tid < 144 owns a second row
        const int j0 = tid, j1 = has2 ? NT + tid : 0;
        const uint4* w0p = (const uint4*)(wc + (size_t)j0 * RPAD);
        const uint4* w1p = (const uint4*)(wc + (size_t)j1 * RPAD);
        const float bi0 = b_ih2[j0] + b_hh2[j0];
        const float bi1 = b_ih2[j1] + b_hh2[j1];
        __syncthreads();   // publishes fp16 conversion (rows written by other threads)

        unsigned ca = 0, cb = 0;
        // ---- prologue: load slot 0
        wait_min4(aw, 1u, ca);
        float cv0 = ld_f(ring1 + l);
        float cv1 = (l < 36) ? ld_f(ring1 + 64 + l) : 0.f;
        // ---- pipelined encode: iter t stores slot t-1, prefetches slot t.
        // ~30 vm-ops/iter -> vmcnt(2) at top certifies slot t-3's store.
        for (int t = 1; t < T; ++t) {
            VMCNT2();
            if (l == 0 && t >= 3) stu(&p2w[w], (unsigned)(t - 2));  // slots <= t-3 valid
            if (t - 1 >= S) wait_ge(b_prog, (unsigned)(t - S), cb); // overwrite guard
            wait_min4(aw, (unsigned)(t + 1), ca);                   // slot t readable
            const float* rp = ring1 + (size_t)(t & smask) * HH;
            float nv0 = ld_f(rp + l);
            float nv1 = (l < 36) ? ld_f(rp + 64 + l) : 0.f;
            float hv0 = cv0, hv1 = cv1;
            float a0 = 0.f, a1 = 0.f, b0 = 0.f, b1 = 0.f;
            REP13(DOTC)                                             // h(t-1)
            float* wpp = ring2 + (size_t)((t - 1) & smask) * ROWS;
            st_wt(wpp + j0, bi0 + a0 + a1);
            if (has2) st_wt(wpp + j1, bi1 + b0 + b1);
            cv0 = nv0; cv1 = nv1;
        }
        // ---- boundary: drain pipeline, then slot T-1 straight.
        VMCNT0();
        if (l == 0) stu(&p2w[w], (unsigned)(T - 1));                // slots <= T-2 valid
        {
            if (T - 1 >= S) wait_ge(b_prog, (unsigned)(T - S), cb);
            float hv0 = cv0, hv1 = cv1;
            float a0 = 0.f, a1 = 0.f, b0 = 0.f, b1 = 0.f;
            REP13(DOTC)                                             // h(T-1)
            float* wpp = ring2 + (size_t)((T - 1) & smask) * ROWS;
            st_wt(wpp + j0, bi0 + a0 + a1);
            if (has2) st_wt(wpp + j1, bi1 + b0 + b1);
        }
        VMCNT0();
        if (l == 0) stu(&p2w[w], (unsigned)T);                      // slots <= T-1 valid
        // ---- future: straight mode (serial chain needs same-step data).
        for (int t = T; t < TOT; ++t) {
            if (t >= S) wait_ge(b_prog, (unsigned)(t - S + 1), cb);
            wait_min4(aw, (unsigned)(t + 1), ca);
            const float* rp = ring1 + (size_t)(t & smask) * HH;
            float hv0 = ld_f(rp + l);
            float hv1 = (l < 36) ? ld_f(rp + 64 + l) : 0.f;
            float a0 = 0.f, a1 = 0.f, b0 = 0.f, b1 = 0.f;
            REP13(DOTC)
            float* wpp = ring2 + (size_t)(t & smask) * ROWS;
            st_wt(wpp + j0, bi0 + a0 + a1);
            if (has2) st_wt(wpp + j1, bi1 + b0 + b1);
            VMCNT0();
            if (l == 0) stu(&p2w[w], (unsigned)(t + 1));
        }
    } else {
        // ================= B: layer-2 recurrence + output =================
        __shared__ __align__(16) float h2s[2][128];
        __shared__ float yp2[2][4];
        const uint4* w0p = (const uint4*)(wc + (size_t)gj0 * RPAD);
        const uint4* w1p = (const uint4*)(wc + (size_t)gj1 * RPAD);
        const float wl = gi_lane ? w_lin[cell] : 0.f;
        const float bl = b_lin[0];
        float c2 = 0.f;
        if (tid < 128) { h2s[0][tid] = 0.f; h2s[1][tid] = 0.f; }
        __syncthreads();   // publishes fp16 conversion + h2s init

        unsigned cpB = 0;
        for (int u = 0; u < TOT; ++u) {
            // Emit previous step's y right after its barrier.
            if (tid == 0 && u > 0) {
                const float* yq = yp2[(u - 1) & 1];
                float y = yq[0] + yq[1] + yq[2] + yq[3] + bl;
                stu(b_prog, (unsigned)u);        // ring2 slot u-1 consumed pre-barrier
                if (u - 1 >= T - 1) {
                    st_wt(&y_slot[(u - 1) - (T - 1)], y);
                    VMCNT0();                    // y_slot store acked before flag
                    stu(y_prog, (unsigned)(u - T + 1));
                }
                out[u - 1] = y;
            }
            float hv0 = h2s[u & 1][l];
            float hv1 = h2s[u & 1][64 + l];
            const float* pp = ring2 + (size_t)(u & smask) * ROWS;
            float preA, preB;
            float a0 = 0.f, a1 = 0.f, b0 = 0.f, b1 = 0.f;
            if (u < T) {     // encode: wait first so pre2 load latency hides under dot
                wait_min4(p2w, (unsigned)(u + 1), cpB);
                preA = ld_f(pp + gj0);
                preB = ld_f(pp + gj1);
                REP13(DOTC)
            } else {         // future: local dot first, then wait
                REP13(DOTC)
                wait_min4(p2w, (unsigned)(u + 1), cpB);
                preA = ld_f(pp + gj0);
                preB = ld_f(pp + gj1);
            }
            float accA = preA + a0 + a1;
            float accB = preB + b0 + b1;
            float vA = go_lane ? fast_tanh(accA) : fast_sigm(accA);
            float vB = fast_sigm(accB);
            float gg = __shfl_xor(vA, 32);
            float go = __shfl_xor(vB, 32);
            float py = 0.f;
            if (gi_lane) {
                c2 = fmaf(vB, c2, vA * gg);
                float h = go * fast_tanh(c2);
                h2s[(u + 1) & 1][cell] = h;
                py = h * wl;
            }
            py += __shfl_down(py, 32);
            py += __shfl_down(py, 16);
            py += __shfl_down(py, 8);
            py += __shfl_down(py, 4);
            py += __shfl_down(py, 2);
            py += __shfl_down(py, 1);
            if (l == 0) yp2[u & 1][w] = py;
            bar();
        }
        if (tid == 0) {   // final step's y
            const float* yq = yp2[(TOT - 1) & 1];
            out[TOT - 1] = yq[0] + yq[1] + yq[2] + yq[3] + bl;
        }
    }
}

extern "C" void kernel_launch(void* const* d_in, const int* in_sizes, int n_in,
                              void* d_out, int out_size, void* d_ws, size_t ws_size,
                              hipStream_t stream) {
    const float* input = (const float*)d_in[0];
    const float* enc_h = (const float*)d_in[1];
    const float* enc_c = (const float*)d_in[2];
    const float* w_ih1 = (const float*)d_in[3];
    const float* w_hh1 = (const float*)d_in[4];
    const float* b_ih1 = (const float*)d_in[5];
    const float* b_hh1 = (const float*)d_in[6];
    const float* w_ih2 = (const float*)d_in[7];
    const float* w_hh2 = (const float*)d_in[8];
    const float* b_ih2 = (const float*)d_in[9];
    const float* b_hh2 = (const float*)d_in[10];
    const float* w_lin = (const float*)d_in[11];
    const float* b_lin = (const float*)d_in[12];
    (void)n_in;

    int T = in_sizes[0];
    int F = out_size - T;
    if (F < 0) F = 0;

    // largest power-of-two ring slot count that fits both rings in d_ws
    // (rings start after the 249.6KB converted-weight area)
    int S = 16;
    while ((size_t)OFF_RING + (size_t)S * 2 * (HH + ROWS) * 4 <= ws_size && S < 8192)
        S <<= 1;

    __half* wfp16 = (__half*)((char*)d_ws + OFF_WC);

    decoder_kernel<<<dim3(3), dim3(NT), 0, stream>>>(
        input, enc_h, enc_c, w_ih1, w_hh1, b_ih1, b_hh1,
        w_ih2, w_hh2, b_ih2, b_hh2, w_lin, b_lin,
        (float*)d_out, (char*)d_ws, wfp16, T, F, S);
}

// Round 13
// 16783.917 us; speedup vs baseline: 1.6107x; 1.6107x over previous
//
#include <hip/hip_runtime.h>
#include <math.h>

// 2-layer LSTM decoder, H=100, T=8192 encode + F=1024 future steps, fp32.
// Three persistent blocks (3 CUs), 256 threads (4 waves) each, 2 rows/thread:
//   block 0 (A) : layer-1 recurrence. gates1 = w_ih1*x + w_hh1*h1 + b. h1 -> ring1.
//   block 1 (A2): feed-forward pre2 = w_ih2*h1 + biases. ring1 -> ring2.
//   block 2 (B) : layer-2 recurrence gates2 = pre2 + w_hh2*h2; y = h2.w_lin + b.
//
// V13: SELF-CERTIFYING TAGGED DATA (fp32 dot reverted to V5's proven best).
// V11/V12 falsified fp16 (both dot forms de-pipeline the load stream: scratch
// round-trips / asm scheduler barriers; +70% twice). V5's residual ~2800
// cy/step non-VALU cost is sync tax: producer vmcnt(0) store-ack waits before
// every flag publish + consumer flag-then-data double LLC round trips (3 hops
// serial in the future phase). V13 removes the entire flag/ack system:
//   * every ring1/ring2/y element = ONE 8-byte atomic (float<<32 | step_tag).
//     Tag+value arrive in the same load -> producers NEVER wait for acks
//     (no vmcnt on any produce path); consumers pay ONE round trip.
//   * per-element tags make partially-written slots race-free; poison
//     0xAAAAAAAA never equals a valid tag (<= 9215); 8B-aligned atomic
//     loads/stores cannot tear.
//   * A2/B: 1-deep prefetch (issue loads -> dot -> verify tags) serves BOTH
//     phases uniformly (no encode/future mode split).
//   * only 2 lazy backpressure counters remain (p2c: A2 consumed ring1;
//     bc: B consumed ring2), published every 64 steps, ack-free (reads
//     self-certify by use; CLOB() stops compiler hoisting).
// Deadlock-free: tag waits point strictly backward in step order; guards have
// S-slack; SPIN_CAP bounds every loop.
// Dot/math/LDS structure byte-equivalent to V5 (absmax 0.0 there).

#define HH 100
#define NT 256
#define ROWS 400
#define SPIN_CAP 2000000u

#define OFF_P2C   0        // unsigned : A2 consumption counter (ring1)
#define OFF_BC    128      // unsigned : B consumption counter (ring2)
#define OFF_Y64   512      // u64[F+1] : tagged y values
#define OFF_RING  16384    // u64 ring1[S][100] then u64 ring2[S][400]

#define LGKM0()  asm volatile("s_waitcnt lgkmcnt(0)" ::: "memory")
#define CLOB()   asm volatile("" ::: "memory")

typedef unsigned long long u64;

__device__ __forceinline__ float rl(float v, int k) {
    return __int_as_float(__builtin_amdgcn_readlane(__float_as_int(v), k));
}
__device__ __forceinline__ unsigned san(unsigned v) { return v > 0x00FFFFFFu ? 0u : v; }
__device__ __forceinline__ unsigned ldu(const unsigned* p) {
    return san(__hip_atomic_load((unsigned*)p, __ATOMIC_RELAXED, __HIP_MEMORY_SCOPE_AGENT));
}
__device__ __forceinline__ void stu(unsigned* p, unsigned v) {
    __hip_atomic_store(p, v, __ATOMIC_RELAXED, __HIP_MEMORY_SCOPE_AGENT);
}
__device__ __forceinline__ u64 ld64(const u64* p) {
    return __hip_atomic_load((u64*)p, __ATOMIC_RELAXED, __HIP_MEMORY_SCOPE_AGENT);
}
__device__ __forceinline__ void st64(u64* p, u64 v) {
    __hip_atomic_store(p, v, __ATOMIC_RELAXED, __HIP_MEMORY_SCOPE_AGENT);
}
__device__ __forceinline__ u64 packft(float f, unsigned tag) {
    return ((u64)__float_as_uint(f) << 32) | (u64)tag;
}
__device__ __forceinline__ float unpackf(u64 v) {
    return __uint_as_float((unsigned)(v >> 32));
}
// Re-poll p until its low word equals tag (value arrives in the same load).
__device__ __forceinline__ void poll_tag(const u64* p, unsigned tag, u64& v) {
    unsigned s = 0;
    while ((unsigned)v != tag) { v = ld64(p); if (++s > SPIN_CAP) break; }
}
// Backpressure counter wait: no vmcnt (certifies nothing; prefetches stay in flight).
__device__ __forceinline__ void wait_cnt(unsigned* p, unsigned need, unsigned& cache) {
    if (cache >= need) return;
    unsigned s = 0;
    do { cache = ldu(p); } while (cache < need && ++s < SPIN_CAP);
}
// Raw workgroup barrier: LDS drain only (ring stores stay in flight, ack-free).
__device__ __forceinline__ void bar() {
    LGKM0();
    __builtin_amdgcn_s_barrier();
    CLOB();
}
__device__ __forceinline__ float fast_sigm(float x) {
    return __builtin_amdgcn_rcpf(1.0f + __expf(-x));
}
__device__ __forceinline__ float fast_tanh(float x) {
    return fmaf(-2.0f, __builtin_amdgcn_rcpf(1.0f + __expf(2.0f * x)), 1.0f);
}

// ---- V5-equivalent fp32 streaming dot: 25 float4 chunks x 2 rows ----
// chunk i covers h[4i..4i+3]; i<16 broadcasts from hv0, i>=16 from hv1 (k<36).
#define REP25(M) M(0) M(1) M(2) M(3) M(4) M(5) M(6) M(7) M(8) M(9) M(10) M(11) \
                 M(12) M(13) M(14) M(15) M(16) M(17) M(18) M(19) M(20) M(21) M(22) M(23) M(24)
#define DOTC(i) { \
    const float hsv = ((i) < 16) ? hv0 : hv1; \
    const int kb = ((i) < 16) ? (4 * (i)) : (4 * ((i) - 16)); \
    float4 Wa = w0p[i]; \
    float4 Wb = w1p[i]; \
    float h0 = rl(hsv, kb), h1 = rl(hsv, kb + 1), h2 = rl(hsv, kb + 2), h3 = rl(hsv, kb + 3); \
    a0 = fmaf(Wa.x, h0, a0); a1 = fmaf(Wa.y, h1, a1); \
    a0 = fmaf(Wa.z, h2, a0); a1 = fmaf(Wa.w, h3, a1); \
    b0 = fmaf(Wb.x, h0, b0); b1 = fmaf(Wb.y, h1, b1); \
    b0 = fmaf(Wb.z, h2, b0); b1 = fmaf(Wb.w, h3, b1); \
}

extern "C" __global__ void __launch_bounds__(NT)
__attribute__((amdgpu_waves_per_eu(1, 1)))
decoder_kernel(const float* __restrict__ input,
               const float* __restrict__ enc_h,
               const float* __restrict__ enc_c,
               const float* __restrict__ w_ih1,
               const float* __restrict__ w_hh1,
               const float* __restrict__ b_ih1,
               const float* __restrict__ b_hh1,
               const float* __restrict__ w_ih2,
               const float* __restrict__ w_hh2,
               const float* __restrict__ b_ih2,
               const float* __restrict__ b_hh2,
               const float* __restrict__ w_lin,
               const float* __restrict__ b_lin,
               float* __restrict__ out,
               char* __restrict__ ws,
               int T, int F, int S)
{
    const int tid = threadIdx.x;
    const int l = tid & 63;
    const int w = tid >> 6;
    unsigned* p2c = (unsigned*)(ws + OFF_P2C);
    unsigned* bc  = (unsigned*)(ws + OFF_BC);
    u64* y64   = (u64*)(ws + OFF_Y64);
    u64* ring1 = (u64*)(ws + OFF_RING);               // [S][100]
    u64* ring2 = ring1 + (size_t)S * HH;              // [S][400]
    const int smask = S - 1;
    const int TOT = T + F;

    // Gate lane mapping (A and B): wave w owns cells 25w..25w+24.
    // lanes 0-24: rows cell (i), cell+100 (f); lanes 32-56: cell+200 (g), cell+300 (o).
    const bool gi_lane = (l < 25);
    const bool go_lane = (l >= 32 && l < 57);
    const int cell = 25 * w + (gi_lane ? l : (go_lane ? (l - 32) : 0));
    const int gj0 = gi_lane ? cell : (go_lane ? cell + 200 : 0);
    const int gj1 = gi_lane ? cell + 100 : (go_lane ? cell + 300 : 0);

    if (blockIdx.x == 0) {
        // ================= A: layer-1 recurrence =================
        __shared__ __align__(16) float h1s[2][128];
        const float4* w0p = (const float4*)(w_hh1 + (size_t)gj0 * HH);
        const float4* w1p = (const float4*)(w_hh1 + (size_t)gj1 * HH);
        const float wx0 = w_ih1[gj0];
        const float wx1 = w_ih1[gj1];
        const float bi0 = b_ih1[gj0] + b_hh1[gj0];
        const float bi1 = b_ih1[gj1] + b_hh1[gj1];
        float cst = gi_lane ? enc_c[cell] : 0.f;
        if (tid < 128) {
            h1s[0][tid] = (tid < HH) ? enc_h[tid] : 0.f;
            h1s[1][tid] = 0.f;
        }
        __syncthreads();

        unsigned cg = 0;
        for (int t = 0; t < TOT; ++t) {
            float x = 0.f;
            if (t < T) x = input[t];
            // ring1 overwrite guard (rare: only when A is >= S ahead of A2)
            if (t >= S) wait_cnt(p2c, (unsigned)(t - S + 1), cg);
            float hv0 = h1s[t & 1][l];
            float hv1 = h1s[t & 1][64 + l];    // slots 100-127 stay 0, never readlaned >=36
            float a0 = 0.f, a1 = 0.f, b0 = 0.f, b1 = 0.f;
            REP25(DOTC)
            float accA = bi0 + a0 + a1;
            float accB = bi1 + b0 + b1;
            if (t >= T) {                       // future: dot done; poll tagged y(t-1)
                const u64* yp = y64 + (t - T);
                u64 v = ld64(yp);
                poll_tag(yp, (unsigned)(t - T), v);
                x = unpackf(v);
            }
            accA = fmaf(x, wx0, accA);
            accB = fmaf(x, wx1, accB);
            float vA = go_lane ? fast_tanh(accA) : fast_sigm(accA);  // i or g
            float vB = fast_sigm(accB);                              // f or o
            float gg = __shfl_xor(vA, 32);
            float go = __shfl_xor(vB, 32);
            if (gi_lane) {
                cst = fmaf(vB, cst, vA * gg);
                float h = go * fast_tanh(cst);
                h1s[(t + 1) & 1][cell] = h;
                st64(&ring1[(size_t)(t & smask) * HH + cell], packft(h, (unsigned)t));
            }
            bar();    // LDS drain only; tagged ring store needs no ack, ever
        }
    } else if (blockIdx.x == 1) {
        // ===== A2: pre2 = w_ih2*h1 + biases. 4 indep waves, tag-driven. =====
        const bool has2 = tid < (ROWS - NT);   // tid < 144 owns a second row
        const int j0 = tid, j1 = has2 ? NT + tid : 0;
        const float4* w0p = (const float4*)(w_ih2 + (size_t)j0 * HH);
        const float4* w1p = (const float4*)(w_ih2 + (size_t)j1 * HH);
        const float bi0 = b_ih2[j0] + b_hh2[j0];
        const float bi1 = b_ih2[j1] + b_hh2[j1];

        unsigned cbc = 0;
        // prologue: issue prefetch of slot 0 (verified inside the loop)
        u64 cv0 = ld64(ring1 + l);
        u64 cv1 = (l < 36) ? ld64(ring1 + 64 + l) : 0;
        // iter t: verify+dot slot t-1, store pre2 t-1, prefetch slot t.
        // Uniform for encode AND future (tag-poll blocks exactly when it must).
        for (int t = 1; t <= TOT; ++t) {
            u64 nv0 = 0, nv1 = 0;
            if (t < TOT) {                      // prefetch slot t (non-blocking issue)
                const u64* q = ring1 + (size_t)(t & smask) * HH;
                nv0 = ld64(q + l);
                if (l < 36) nv1 = ld64(q + 64 + l);
            }
            // verify slot t-1 tags (usually first-try in encode)
            const u64* o = ring1 + (size_t)((t - 1) & smask) * HH;
            const unsigned tg = (unsigned)(t - 1);
            poll_tag(o + l, tg, cv0);
            float hv0 = unpackf(cv0);
            float hv1 = 0.f;
            if (l < 36) { poll_tag(o + 64 + l, tg, cv1); hv1 = unpackf(cv1); }
            float a0 = 0.f, a1 = 0.f, b0 = 0.f, b1 = 0.f;
            REP25(DOTC)                         // h(t-1)
            // ring2 overwrite guard (rare)
            if (t - 1 >= S) wait_cnt(bc, (unsigned)(t - S), cbc);
            u64* wp = ring2 + (size_t)((t - 1) & smask) * ROWS;
            st64(wp + j0, packft(bi0 + a0 + a1, tg));
            if (has2) st64(wp + j1, packft(bi1 + b0 + b1, tg));
            cv0 = nv0; cv1 = nv1;
            // lazy consumption publish (ack-free; CLOB stops hoisting)
            if (tid == 0 && (t & 63) == 0) { CLOB(); stu(p2c, (unsigned)t); }
        }
        CLOB();
        if (tid == 0) stu(p2c, (unsigned)(TOT + 1));
    } else {
        // ================= B: layer-2 recurrence + output =================
        __shared__ __align__(16) float h2s[2][128];
        __shared__ float yp2[2][4];
        const float4* w0p = (const float4*)(w_hh2 + (size_t)gj0 * HH);
        const float4* w1p = (const float4*)(w_hh2 + (size_t)gj1 * HH);
        const float wl = gi_lane ? w_lin[cell] : 0.f;
        const float bl = b_lin[0];
        float c2 = 0.f;
        if (tid < 128) { h2s[0][tid] = 0.f; h2s[1][tid] = 0.f; }
        __syncthreads();

        for (int u = 0; u < TOT; ++u) {
            // prefetch tagged pre2 slot u (non-blocking issue)
            const u64* pp = ring2 + (size_t)(u & smask) * ROWS;
            u64 pv0 = ld64(pp + gj0);
            u64 pv1 = ld64(pp + gj1);
            float hv0 = h2s[u & 1][l];
            float hv1 = h2s[u & 1][64 + l];
            float a0 = 0.f, a1 = 0.f, b0 = 0.f, b1 = 0.f;
            REP25(DOTC)                         // local h2 dot (independent of pre2)
            const unsigned tg = (unsigned)u;
            poll_tag(pp + gj0, tg, pv0);
            poll_tag(pp + gj1, tg, pv1);
            float accA = unpackf(pv0) + a0 + a1;
            float accB = unpackf(pv1) + b0 + b1;
            float vA = go_lane ? fast_tanh(accA) : fast_sigm(accA);
            float vB = fast_sigm(accB);
            float gg = __shfl_xor(vA, 32);
            float go = __shfl_xor(vB, 32);
            float py = 0.f;
            if (gi_lane) {
                c2 = fmaf(vB, c2, vA * gg);
                float h = go * fast_tanh(c2);
                h2s[(u + 1) & 1][cell] = h;
                py = h * wl;
            }
            py += __shfl_down(py, 32);
            py += __shfl_down(py, 16);
            py += __shfl_down(py, 8);
            py += __shfl_down(py, 4);
            py += __shfl_down(py, 2);
            py += __shfl_down(py, 1);
            if (l == 0) yp2[u & 1][w] = py;
            bar();
            // emit y_u immediately (tagged single store -> zero producer wait)
            if (tid == 0) {
                const float* yq = yp2[u & 1];
                float y = yq[0] + yq[1] + yq[2] + yq[3] + bl;
                out[u] = y;
                if (u >= T - 1) st64(&y64[u - (T - 1)], packft(y, (unsigned)(u - (T - 1))));
                if ((u & 63) == 0) { CLOB(); stu(bc, (unsigned)(u + 1)); }
            }
        }
        CLOB();
        if (tid == 0) stu(bc, (unsigned)(TOT + 1));
    }
}

extern "C" void kernel_launch(void* const* d_in, const int* in_sizes, int n_in,
                              void* d_out, int out_size, void* d_ws, size_t ws_size,
                              hipStream_t stream) {
    const float* input = (const float*)d_in[0];
    const float* enc_h = (const float*)d_in[1];
    const float* enc_c = (const float*)d_in[2];
    const float* w_ih1 = (const float*)d_in[3];
    const float* w_hh1 = (const float*)d_in[4];
    const float* b_ih1 = (const float*)d_in[5];
    const float* b_hh1 = (const float*)d_in[6];
    const float* w_ih2 = (const float*)d_in[7];
    const float* w_hh2 = (const float*)d_in[8];
    const float* b_ih2 = (const float*)d_in[9];
    const float* b_hh2 = (const float*)d_in[10];
    const float* w_lin = (const float*)d_in[11];
    const float* b_lin = (const float*)d_in[12];
    (void)n_in;

    int T = in_sizes[0];
    int F = out_size - T;
    if (F < 0) F = 0;

    // rings: (100+400) u64 = 4000 B per slot (same footprint as V5's fp32 rings)
    int S = 16;
    while ((size_t)OFF_RING + (size_t)S * (HH + ROWS) * 8 <= ws_size && S < 8192)
        S <<= 1;

    decoder_kernel<<<dim3(3), dim3(NT), 0, stream>>>(
        input, enc_h, enc_c, w_ih1, w_hh1, b_ih1, b_hh1,
        w_ih2, w_hh2, b_ih2, b_hh2, w_lin, b_lin,
        (float*)d_out, (char*)d_ws, T, F, S);
}